// Round 2
// 665.666 us; speedup vs baseline: 1.3013x; 1.3013x over previous
//
#include <hip/hip_runtime.h>

// ---------------------------------------------------------------------------
// Round 6: round-5 design, crash-hardened.
//  - Suspected round-5 failure: workspace overflow (77.3MB needed, f32 P1/P2).
//    P1/P2/Q1 now bf16 (12.8MB each) -> 51.7MB total; precision impact ~1e-3
//    on pre-activations (below existing bf16 MFMA rounding).
//  - ws_size guard: if workspace < 51.7MB, fall back to the verbatim round-4
//    pe/node kernels (proven correct at 866us, 26.1MB).
//  - Primary: pe zero-barrier, W1c+W2 LDS-resident (80KB, 2 blocks/CU),
//    P1[snd]+P2[rcv] gathered straight into the accumulator, K=128 GEMM1.
//    node: Q1 precomputed, all weights resident (112KB), zero barriers.
// ---------------------------------------------------------------------------

#define N_NODES 50000
#define N_EDGES 400000
#define HID 128
#define LN_EPS 1e-5f

typedef unsigned short u16;
typedef __attribute__((ext_vector_type(8))) short short8;   // 8 x bf16
typedef __attribute__((ext_vector_type(4))) float floatx4;  // MFMA C/D

__device__ __forceinline__ u16 f2bf(float f) {
    union { float f; unsigned int i; } v; v.f = f;
    unsigned int x = v.i;
    return (u16)((x + 0x7FFFu + ((x >> 16) & 1u)) >> 16);  // RNE
}
__device__ __forceinline__ float bf2f(u16 u) {
    union { unsigned int i; float f; } v; v.i = ((unsigned int)u) << 16;
    return v.f;
}
__device__ __forceinline__ float siluf(float x) { return x * (1.0f / (1.0f + __expf(-x))); }
__device__ __forceinline__ float sigmf(float x) { return 1.0f / (1.0f + __expf(-x)); }

__device__ __forceinline__ short8 pack8(const float* __restrict__ p) {
    union { u16 u[8]; short8 v; } o;
    float4 a = *(const float4*)p;
    float4 b = *(const float4*)(p + 4);
    o.u[0] = f2bf(a.x); o.u[1] = f2bf(a.y); o.u[2] = f2bf(a.z); o.u[3] = f2bf(a.w);
    o.u[4] = f2bf(b.x); o.u[5] = f2bf(b.y); o.u[6] = f2bf(b.z); o.u[7] = f2bf(b.w);
    return o.v;
}
__device__ __forceinline__ short8 pack8s(const float* __restrict__ p, float sc) {
    union { u16 u[8]; short8 v; } o;
    float4 a = *(const float4*)p;
    float4 b = *(const float4*)(p + 4);
    o.u[0] = f2bf(a.x * sc); o.u[1] = f2bf(a.y * sc); o.u[2] = f2bf(a.z * sc); o.u[3] = f2bf(a.w * sc);
    o.u[4] = f2bf(b.x * sc); o.u[5] = f2bf(b.y * sc); o.u[6] = f2bf(b.z * sc); o.u[7] = f2bf(b.w * sc);
    return o.v;
}

// 128-wide LDS row (256B), 16B chunks XOR-swizzled by row (no padding needed).
__device__ __forceinline__ char* swzp(const void* base, int row, int b) {
    return (char*)base + row * 256 + ((b & 15) | ((((b >> 4) ^ row) & 15) << 4));
}

// W fp32 (K x N) row-major -> WT bf16 (N x K) row-major
__global__ void k_prepT(const float* __restrict__ src, u16* __restrict__ dst, int K, int N) {
    int i = blockIdx.x * blockDim.x + threadIdx.x;
    if (i < K * N) {
        int k = i / N, n = i - k * N;
        dst[n * K + k] = f2bf(src[i]);
    }
}

// ---------------- Stage 1: ee FFN + LN -> edge_lat (zero-barrier loop) -----
__launch_bounds__(256)
__global__ void k_edge_ee(const float* __restrict__ ef,
                          const float* __restrict__ W1, const float* __restrict__ b1v,
                          const u16* __restrict__ W2T, const float* __restrict__ b2v,
                          const float* __restrict__ g, const float* __restrict__ be,
                          float* __restrict__ outEL) {
    __shared__ __align__(16) u16 sW2[128 * 136];
    __shared__ float sW1[384];
    __shared__ float sB1[128];
    const int t = threadIdx.x;
    const int lane = t & 63, w = t >> 6;
    const int l15 = lane & 15, quad = lane >> 4;

    for (int i = t; i < 2048; i += 256) {
        int n = i >> 4, q = i & 15;
        *(uint4*)&sW2[n * 136 + q * 8] = *(const uint4*)&W2T[n * 128 + q * 8];
    }
    for (int i = t; i < 384; i += 256) sW1[i] = W1[i];
    if (t < 128) sB1[t] = b1v[t];
    __syncthreads();

    float b2r[8], gr[8], ber[8];
    #pragma unroll
    for (int nt = 0; nt < 8; ++nt) {
        int col = nt * 16 + l15;
        b2r[nt] = b2v[col]; gr[nt] = g[col]; ber[nt] = be[col];
    }

    for (int tile = blockIdx.x; tile < N_EDGES / 64; tile += gridDim.x) {
        const int e0 = tile * 64;
        const int em = e0 + w * 16 + l15;
        float f0 = ef[em * 3 + 0], f1 = ef[em * 3 + 1], f2 = ef[em * 3 + 2];
        short8 ha[4];
        #pragma unroll
        for (int ks = 0; ks < 4; ++ks) {          // h directly in A-frag layout
            union { u16 u[8]; short8 v; } hh;
            #pragma unroll
            for (int jj = 0; jj < 8; ++jj) {
                int j = ks * 32 + quad * 8 + jj;
                float x = sB1[j] + f0 * sW1[j] + f1 * sW1[128 + j] + f2 * sW1[256 + j];
                hh.u[jj] = f2bf(siluf(x));
            }
            ha[ks] = hh.v;
        }
        floatx4 acc[8];
        #pragma unroll
        for (int nt = 0; nt < 8; ++nt) acc[nt] = (floatx4){0.f, 0.f, 0.f, 0.f};
        #pragma unroll
        for (int ks = 0; ks < 4; ++ks) {
            #pragma unroll
            for (int nt = 0; nt < 8; ++nt) {
                short8 bv = *(const short8*)&sW2[(nt * 16 + l15) * 136 + ks * 32 + quad * 8];
                acc[nt] = __builtin_amdgcn_mfma_f32_16x16x32_bf16(ha[ks], bv, acc[nt], 0, 0, 0);
            }
        }
        float sum[4] = {0, 0, 0, 0}, sq[4] = {0, 0, 0, 0};
        #pragma unroll
        for (int nt = 0; nt < 8; ++nt)
            #pragma unroll
            for (int rr = 0; rr < 4; ++rr) {
                float v = acc[nt][rr] + b2r[nt];
                acc[nt][rr] = v; sum[rr] += v; sq[rr] += v * v;
            }
        #pragma unroll
        for (int m = 1; m < 16; m <<= 1)
            #pragma unroll
            for (int rr = 0; rr < 4; ++rr) {
                sum[rr] += __shfl_xor(sum[rr], m);
                sq[rr]  += __shfl_xor(sq[rr], m);
            }
        float mu[4], rs[4];
        #pragma unroll
        for (int rr = 0; rr < 4; ++rr) {
            mu[rr] = sum[rr] * (1.0f / HID);
            float var = fmaxf(sq[rr] * (1.0f / HID) - mu[rr] * mu[rr], 0.f);
            rs[rr] = rsqrtf(var + LN_EPS);
        }
        #pragma unroll
        for (int nt = 0; nt < 8; ++nt) {
            int col = nt * 16 + l15;
            #pragma unroll
            for (int rr = 0; rr < 4; ++rr) {
                int row = e0 + w * 16 + quad * 4 + rr;
                outEL[(size_t)row * HID + col] = (acc[nt][rr] - mu[rr]) * rs[rr] * gr[nt] + ber[nt];
            }
        }
    }
}

// ---------------- Dense helper: out[M x 128] = bf16(A[M x 128] @ W) --------
// WT is bf16 (128 rows x ldw), we use columns [koff, koff+128).
__launch_bounds__(256)
__global__ void k_gemm128(const float* __restrict__ A, const u16* __restrict__ WT,
                          int ldw, int koff, u16* __restrict__ out) {
    __shared__ __align__(16) u16 sW[128 * 128];
    const int t = threadIdx.x;
    const int lane = t & 63, w = t >> 6;
    const int l15 = lane & 15, quad = lane >> 4;
    for (int i = t; i < 2048; i += 256) {
        int n = i >> 4, q = i & 15;
        *(uint4*)swzp(sW, n, q * 16) = *(const uint4*)&WT[n * ldw + koff + q * 8];
    }
    __syncthreads();
    const int NT = (N_NODES + 63) / 64;
    for (int tile = blockIdx.x; tile < NT; tile += gridDim.x) {
        const int n0 = tile * 64;
        const int arow = n0 + w * 16 + l15;
        const int ac = arow < N_NODES ? arow : 0;
        short8 a[4];
        #pragma unroll
        for (int ks = 0; ks < 4; ++ks)
            a[ks] = pack8(&A[(size_t)ac * HID + ks * 32 + quad * 8]);
        floatx4 acc[8];
        #pragma unroll
        for (int nt = 0; nt < 8; ++nt) acc[nt] = (floatx4){0.f, 0.f, 0.f, 0.f};
        #pragma unroll
        for (int ks = 0; ks < 4; ++ks)
            #pragma unroll
            for (int nt = 0; nt < 8; ++nt) {
                short8 bv = *(const short8*)swzp(sW, nt * 16 + l15, ks * 64 + quad * 16);
                acc[nt] = __builtin_amdgcn_mfma_f32_16x16x32_bf16(a[ks], bv, acc[nt], 0, 0, 0);
            }
        #pragma unroll
        for (int nt = 0; nt < 8; ++nt) {
            int col = nt * 16 + l15;
            #pragma unroll
            for (int rr = 0; rr < 4; ++rr) {
                int orow = n0 + w * 16 + quad * 4 + rr;
                if (orow < N_NODES) out[(size_t)orow * HID + col] = f2bf(acc[nt][rr]);
            }
        }
    }
}

// ---------------- Stage 2 (primary): pe FFN + LN + scatter, zero barriers --
__launch_bounds__(256)
__global__ void k_edge_pe(const int* __restrict__ eidx,
                          const u16* __restrict__ P1, const u16* __restrict__ P2,
                          const float* __restrict__ el,
                          const u16* __restrict__ W1T, const float* __restrict__ b1v,
                          const u16* __restrict__ W2T, const float* __restrict__ b2v,
                          const float* __restrict__ g, const float* __restrict__ be,
                          float* __restrict__ seg, float* __restrict__ cnt) {
    __shared__ __align__(16) u16 sW1[128 * 128];   // W1c (k 256..383), swizzled
    __shared__ __align__(16) u16 sW2[128 * 128];   // W2, swizzled
    __shared__ __align__(16) u16 sH[4][16 * 128];  // per-wave h transpose, swizzled
    const int t = threadIdx.x;
    const int lane = t & 63, w = t >> 6;
    const int l15 = lane & 15, quad = lane >> 4;

    for (int i = t; i < 2048; i += 256) {
        int n = i >> 4, q = i & 15;
        *(uint4*)swzp(sW1, n, q * 16) = *(const uint4*)&W1T[n * 384 + 256 + q * 8];
        *(uint4*)swzp(sW2, n, q * 16) = *(const uint4*)&W2T[n * 128 + q * 8];
    }
    float b1r[8], b2r[8], gr[8], ber[8];
    #pragma unroll
    for (int nt = 0; nt < 8; ++nt) {
        int col = nt * 16 + l15;
        b1r[nt] = b1v[col]; b2r[nt] = b2v[col]; gr[nt] = g[col]; ber[nt] = be[col];
    }
    __syncthreads();

    for (int tile = blockIdx.x; tile < N_EDGES / 64; tile += gridDim.x) {
        const int e0 = tile * 64;
        const int em = e0 + w * 16 + l15;          // A-frag row (by l15)
        int snd[4], rcv[4];
        #pragma unroll
        for (int rr = 0; rr < 4; ++rr) {           // C rows (by quad*4+rr)
            int e = e0 + w * 16 + quad * 4 + rr;
            int2 p = *(const int2*)&eidx[e * 2];
            snd[rr] = p.x; rcv[rr] = p.y;
        }
        // init acc with b1 + gathered per-node partials (lands in C layout)
        floatx4 acc[8];
        #pragma unroll
        for (int nt = 0; nt < 8; ++nt) {
            int col = nt * 16 + l15;
            #pragma unroll
            for (int rr = 0; rr < 4; ++rr)
                acc[nt][rr] = b1r[nt] + bf2f(P1[(size_t)snd[rr] * HID + col])
                                      + bf2f(P2[(size_t)rcv[rr] * HID + col]);
        }
        // el A-frags (contiguous rows)
        short8 a[4];
        #pragma unroll
        for (int ks = 0; ks < 4; ++ks)
            a[ks] = pack8(&el[(size_t)em * HID + ks * 32 + quad * 8]);
        #pragma unroll
        for (int ks = 0; ks < 4; ++ks)
            #pragma unroll
            for (int nt = 0; nt < 8; ++nt) {
                short8 bv = *(const short8*)swzp(sW1, nt * 16 + l15, ks * 64 + quad * 16);
                acc[nt] = __builtin_amdgcn_mfma_f32_16x16x32_bf16(a[ks], bv, acc[nt], 0, 0, 0);
            }
        // h = silu(acc) -> per-wave transpose in sH (wave-private, no barrier)
        #pragma unroll
        for (int nt = 0; nt < 8; ++nt) {
            #pragma unroll
            for (int rr = 0; rr < 4; ++rr)
                *(u16*)swzp(sH[w], quad * 4 + rr, 32 * nt + 2 * l15) = f2bf(siluf(acc[nt][rr]));
        }
        short8 ha[4];
        #pragma unroll
        for (int ks = 0; ks < 4; ++ks)
            ha[ks] = *(const short8*)swzp(sH[w], l15, ks * 64 + quad * 16);
        floatx4 acc2[8];
        #pragma unroll
        for (int nt = 0; nt < 8; ++nt) acc2[nt] = (floatx4){0.f, 0.f, 0.f, 0.f};
        #pragma unroll
        for (int ks = 0; ks < 4; ++ks)
            #pragma unroll
            for (int nt = 0; nt < 8; ++nt) {
                short8 bv = *(const short8*)swzp(sW2, nt * 16 + l15, ks * 64 + quad * 16);
                acc2[nt] = __builtin_amdgcn_mfma_f32_16x16x32_bf16(ha[ks], bv, acc2[nt], 0, 0, 0);
            }
        // LN + atomic scatter
        float sum[4] = {0, 0, 0, 0}, sq[4] = {0, 0, 0, 0};
        #pragma unroll
        for (int nt = 0; nt < 8; ++nt)
            #pragma unroll
            for (int rr = 0; rr < 4; ++rr) {
                float v = acc2[nt][rr] + b2r[nt];
                acc2[nt][rr] = v; sum[rr] += v; sq[rr] += v * v;
            }
        #pragma unroll
        for (int m = 1; m < 16; m <<= 1)
            #pragma unroll
            for (int rr = 0; rr < 4; ++rr) {
                sum[rr] += __shfl_xor(sum[rr], m);
                sq[rr]  += __shfl_xor(sq[rr], m);
            }
        float mu[4], rs[4];
        #pragma unroll
        for (int rr = 0; rr < 4; ++rr) {
            mu[rr] = sum[rr] * (1.0f / HID);
            float var = fmaxf(sq[rr] * (1.0f / HID) - mu[rr] * mu[rr], 0.f);
            rs[rr] = rsqrtf(var + LN_EPS);
        }
        #pragma unroll
        for (int nt = 0; nt < 8; ++nt) {
            int col = nt * 16 + l15;
            #pragma unroll
            for (int rr = 0; rr < 4; ++rr) {
                float v = (acc2[nt][rr] - mu[rr]) * rs[rr] * gr[nt] + ber[nt];
                atomicAdd(&seg[(size_t)rcv[rr] * HID + col], v);
            }
        }
        if (l15 == 0) {
            #pragma unroll
            for (int rr = 0; rr < 4; ++rr) atomicAdd(&cnt[rcv[rr]], 1.0f);
        }
    }
}

// ---------------- Stage 3 (primary): node FFNs, zero barriers --------------
__launch_bounds__(256)
__global__ void k_node(const u16* __restrict__ Q1,
                       const float* __restrict__ seg, const float* __restrict__ cnt,
                       const u16* __restrict__ W1T, const float* __restrict__ b1v,
                       const u16* __restrict__ W2T, const float* __restrict__ b2v,
                       const float* __restrict__ g, const float* __restrict__ be,
                       const u16* __restrict__ noW1T, const float* __restrict__ nob1,
                       const float* __restrict__ noW2, const float* __restrict__ nob2,
                       float* __restrict__ outN) {
    __shared__ __align__(16) u16 sW1[128 * 128];   // pnW1b (k 128..255), swizzled
    __shared__ __align__(16) u16 sW2[128 * 128];   // pnW2, swizzled
    __shared__ __align__(16) u16 sNo[128 * 128];   // noW1, swizzled
    __shared__ __align__(16) u16 sH[4][16 * 128];  // per-wave transpose
    const int t = threadIdx.x;
    const int lane = t & 63, w = t >> 6;
    const int l15 = lane & 15, quad = lane >> 4;

    for (int i = t; i < 2048; i += 256) {
        int n = i >> 4, q = i & 15;
        *(uint4*)swzp(sW1, n, q * 16) = *(const uint4*)&W1T[n * 256 + 128 + q * 8];
        *(uint4*)swzp(sW2, n, q * 16) = *(const uint4*)&W2T[n * 128 + q * 8];
        *(uint4*)swzp(sNo, n, q * 16) = *(const uint4*)&noW1T[n * 128 + q * 8];
    }
    float b1r[8], b2r[8], gr[8], ber[8], nob1r[8], w2r[8][3];
    #pragma unroll
    for (int nt = 0; nt < 8; ++nt) {
        int col = nt * 16 + l15;
        b1r[nt] = b1v[col]; b2r[nt] = b2v[col]; gr[nt] = g[col]; ber[nt] = be[col];
        nob1r[nt] = nob1[col];
        #pragma unroll
        for (int c = 0; c < 3; ++c) w2r[nt][c] = noW2[col * 3 + c];
    }
    float nob2r[3] = {nob2[0], nob2[1], nob2[2]};
    __syncthreads();

    const int NT = (N_NODES + 63) / 64;
    for (int tile = blockIdx.x; tile < NT; tile += gridDim.x) {
        const int n0 = tile * 64;
        const int node = n0 + w * 16 + l15;        // A-frag row
        const int nc = node < N_NODES ? node : 0;
        float inv = 1.0f / fmaxf(cnt[nc], 1.0f);
        short8 a[4];
        #pragma unroll
        for (int ks = 0; ks < 4; ++ks)
            a[ks] = pack8s(&seg[(size_t)nc * HID + ks * 32 + quad * 8], inv);
        floatx4 acc[8];
        int crow[4];
        #pragma unroll
        for (int rr = 0; rr < 4; ++rr) {
            int r = n0 + w * 16 + quad * 4 + rr;
            crow[rr] = r;
            r = r < N_NODES ? r : 0;
            #pragma unroll
            for (int nt = 0; nt < 8; ++nt)
                acc[nt][rr] = b1r[nt] + bf2f(Q1[(size_t)r * HID + nt * 16 + l15]);
        }
        #pragma unroll
        for (int ks = 0; ks < 4; ++ks)
            #pragma unroll
            for (int nt = 0; nt < 8; ++nt) {
                short8 bv = *(const short8*)swzp(sW1, nt * 16 + l15, ks * 64 + quad * 16);
                acc[nt] = __builtin_amdgcn_mfma_f32_16x16x32_bf16(a[ks], bv, acc[nt], 0, 0, 0);
            }
        // silu -> sH (wave-private)
        #pragma unroll
        for (int nt = 0; nt < 8; ++nt)
            #pragma unroll
            for (int rr = 0; rr < 4; ++rr)
                *(u16*)swzp(sH[w], quad * 4 + rr, 32 * nt + 2 * l15) = f2bf(siluf(acc[nt][rr]));
        short8 ha[4];
        #pragma unroll
        for (int ks = 0; ks < 4; ++ks)
            ha[ks] = *(const short8*)swzp(sH[w], l15, ks * 64 + quad * 16);
        floatx4 acc2[8];
        #pragma unroll
        for (int nt = 0; nt < 8; ++nt) acc2[nt] = (floatx4){0.f, 0.f, 0.f, 0.f};
        #pragma unroll
        for (int ks = 0; ks < 4; ++ks)
            #pragma unroll
            for (int nt = 0; nt < 8; ++nt) {
                short8 bv = *(const short8*)swzp(sW2, nt * 16 + l15, ks * 64 + quad * 16);
                acc2[nt] = __builtin_amdgcn_mfma_f32_16x16x32_bf16(ha[ks], bv, acc2[nt], 0, 0, 0);
            }
        // LN -> new_node (bf16) -> sH
        float sum[4] = {0, 0, 0, 0}, sq[4] = {0, 0, 0, 0};
        #pragma unroll
        for (int nt = 0; nt < 8; ++nt)
            #pragma unroll
            for (int rr = 0; rr < 4; ++rr) {
                float v = acc2[nt][rr] + b2r[nt];
                acc2[nt][rr] = v; sum[rr] += v; sq[rr] += v * v;
            }
        #pragma unroll
        for (int m = 1; m < 16; m <<= 1)
            #pragma unroll
            for (int rr = 0; rr < 4; ++rr) {
                sum[rr] += __shfl_xor(sum[rr], m);
                sq[rr]  += __shfl_xor(sq[rr], m);
            }
        #pragma unroll
        for (int nt = 0; nt < 8; ++nt)
            #pragma unroll
            for (int rr = 0; rr < 4; ++rr) {
                float mu = sum[rr] * (1.0f / HID);
                float var = fmaxf(sq[rr] * (1.0f / HID) - mu * mu, 0.f);
                float rsn = rsqrtf(var + LN_EPS);
                *(u16*)swzp(sH[w], quad * 4 + rr, 32 * nt + 2 * l15) =
                    f2bf((acc2[nt][rr] - mu) * rsn * gr[nt] + ber[nt]);
            }
        short8 h2[4];
        #pragma unroll
        for (int ks = 0; ks < 4; ++ks)
            h2[ks] = *(const short8*)swzp(sH[w], l15, ks * 64 + quad * 16);
        floatx4 acc3[8];
        #pragma unroll
        for (int nt = 0; nt < 8; ++nt) acc3[nt] = (floatx4){0.f, 0.f, 0.f, 0.f};
        #pragma unroll
        for (int ks = 0; ks < 4; ++ks)
            #pragma unroll
            for (int nt = 0; nt < 8; ++nt) {
                short8 bv = *(const short8*)swzp(sNo, nt * 16 + l15, ks * 64 + quad * 16);
                acc3[nt] = __builtin_amdgcn_mfma_f32_16x16x32_bf16(h2[ks], bv, acc3[nt], 0, 0, 0);
            }
        float p[4][3] = {{0,0,0},{0,0,0},{0,0,0},{0,0,0}};
        #pragma unroll
        for (int nt = 0; nt < 8; ++nt)
            #pragma unroll
            for (int rr = 0; rr < 4; ++rr) {
                float h3 = sigmf(acc3[nt][rr] + nob1r[nt]);
                #pragma unroll
                for (int c = 0; c < 3; ++c) p[rr][c] += h3 * w2r[nt][c];
            }
        #pragma unroll
        for (int m = 1; m < 16; m <<= 1)
            #pragma unroll
            for (int rr = 0; rr < 4; ++rr)
                #pragma unroll
                for (int c = 0; c < 3; ++c) p[rr][c] += __shfl_xor(p[rr][c], m);
        if (l15 < 3) {
            #pragma unroll
            for (int rr = 0; rr < 4; ++rr)
                if (crow[rr] < N_NODES)
                    outN[(size_t)crow[rr] * 3 + l15] = p[rr][l15] + nob2r[l15];
        }
    }
}

// ======================= FALLBACK (verbatim round-4, proven) ===============
__launch_bounds__(256)
__global__ void k_edge_pe_fb(const int* __restrict__ eidx,
                             const float* __restrict__ nlat, const float* __restrict__ nfeat,
                             const float* __restrict__ el,
                             const u16* __restrict__ W1T, const float* __restrict__ b1v,
                             const u16* __restrict__ W2T, const float* __restrict__ b2v,
                             const float* __restrict__ g, const float* __restrict__ be,
                             float* __restrict__ seg, float* __restrict__ cnt) {
    __shared__ __align__(16) u16 sWk[2][128 * 40];
    __shared__ __align__(16) u16 sH[4][16 * 136];
    __shared__ int sRecv[64];
    const int t = threadIdx.x;
    const int lane = t & 63, w = t >> 6;
    const int l15 = lane & 15, quad = lane >> 4;

    float b1r[8], b2r[8], gr[8], ber[8];
    #pragma unroll
    for (int nt = 0; nt < 8; ++nt) {
        int col = nt * 16 + l15;
        b1r[nt] = b1v[col]; b2r[nt] = b2v[col]; gr[nt] = g[col]; ber[nt] = be[col];
    }

    for (int tile = blockIdx.x; tile < N_EDGES / 64; tile += gridDim.x) {
        const int e0 = tile * 64;
        __syncthreads();
        if (t < 64) sRecv[t] = eidx[(e0 + t) * 2 + 1];
        const int em = e0 + w * 16 + l15;
        const int snd = eidx[em * 2], rcv = eidx[em * 2 + 1];
        short8 a[12];
        #pragma unroll
        for (int ks = 0; ks < 4; ++ks) {
            a[ks]     = pack8(&nlat[(size_t)snd * HID + ks * 32 + quad * 8]);
            a[4 + ks] = pack8(&nfeat[(size_t)rcv * HID + ks * 32 + quad * 8]);
            a[8 + ks] = pack8(&el[(size_t)em * HID + ks * 32 + quad * 8]);
        }
        #pragma unroll
        for (int i = t; i < 512; i += 256) {
            int n = i >> 2, q = i & 3;
            *(uint4*)&sWk[0][n * 40 + q * 8] = *(const uint4*)&W1T[n * 384 + q * 8];
        }
        __syncthreads();
        floatx4 acc[8];
        #pragma unroll
        for (int nt = 0; nt < 8; ++nt) acc[nt] = (floatx4){0.f, 0.f, 0.f, 0.f};
        #pragma unroll
        for (int ks = 0; ks < 12; ++ks) {
            if (ks < 11) {
                #pragma unroll
                for (int i = t; i < 512; i += 256) {
                    int n = i >> 2, q = i & 3;
                    *(uint4*)&sWk[(ks + 1) & 1][n * 40 + q * 8] =
                        *(const uint4*)&W1T[n * 384 + (ks + 1) * 32 + q * 8];
                }
            }
            const u16* B = sWk[ks & 1];
            #pragma unroll
            for (int nt = 0; nt < 8; ++nt) {
                short8 bv = *(const short8*)&B[(nt * 16 + l15) * 40 + quad * 8];
                acc[nt] = __builtin_amdgcn_mfma_f32_16x16x32_bf16(a[ks], bv, acc[nt], 0, 0, 0);
            }
            __syncthreads();
        }
        #pragma unroll
        for (int nt = 0; nt < 8; ++nt) {
            int col = nt * 16 + l15;
            #pragma unroll
            for (int rr = 0; rr < 4; ++rr)
                sH[w][(quad * 4 + rr) * 136 + col] = f2bf(siluf(acc[nt][rr] + b1r[nt]));
        }
        #pragma unroll
        for (int i = t; i < 512; i += 256) {
            int n = i >> 2, q = i & 3;
            *(uint4*)&sWk[0][n * 40 + q * 8] = *(const uint4*)&W2T[n * 128 + q * 8];
        }
        __syncthreads();
        short8 ha[4];
        #pragma unroll
        for (int ks = 0; ks < 4; ++ks)
            ha[ks] = *(const short8*)&sH[w][l15 * 136 + ks * 32 + quad * 8];
        floatx4 acc2[8];
        #pragma unroll
        for (int nt = 0; nt < 8; ++nt) acc2[nt] = (floatx4){0.f, 0.f, 0.f, 0.f};
        #pragma unroll
        for (int ks = 0; ks < 4; ++ks) {
            if (ks < 3) {
                #pragma unroll
                for (int i = t; i < 512; i += 256) {
                    int n = i >> 2, q = i & 3;
                    *(uint4*)&sWk[(ks + 1) & 1][n * 40 + q * 8] =
                        *(const uint4*)&W2T[n * 128 + (ks + 1) * 32 + q * 8];
                }
            }
            const u16* B = sWk[ks & 1];
            #pragma unroll
            for (int nt = 0; nt < 8; ++nt) {
                short8 bv = *(const short8*)&B[(nt * 16 + l15) * 40 + quad * 8];
                acc2[nt] = __builtin_amdgcn_mfma_f32_16x16x32_bf16(ha[ks], bv, acc2[nt], 0, 0, 0);
            }
            if (ks < 3) __syncthreads();
        }
        float sum[4] = {0, 0, 0, 0}, sq[4] = {0, 0, 0, 0};
        #pragma unroll
        for (int nt = 0; nt < 8; ++nt)
            #pragma unroll
            for (int rr = 0; rr < 4; ++rr) {
                float v = acc2[nt][rr] + b2r[nt];
                acc2[nt][rr] = v; sum[rr] += v; sq[rr] += v * v;
            }
        #pragma unroll
        for (int m = 1; m < 16; m <<= 1)
            #pragma unroll
            for (int rr = 0; rr < 4; ++rr) {
                sum[rr] += __shfl_xor(sum[rr], m);
                sq[rr]  += __shfl_xor(sq[rr], m);
            }
        float mu[4], rs[4];
        int rrow[4];
        #pragma unroll
        for (int rr = 0; rr < 4; ++rr) {
            mu[rr] = sum[rr] * (1.0f / HID);
            float var = fmaxf(sq[rr] * (1.0f / HID) - mu[rr] * mu[rr], 0.f);
            rs[rr] = rsqrtf(var + LN_EPS);
            rrow[rr] = sRecv[w * 16 + quad * 4 + rr];
        }
        #pragma unroll
        for (int nt = 0; nt < 8; ++nt) {
            int col = nt * 16 + l15;
            #pragma unroll
            for (int rr = 0; rr < 4; ++rr) {
                float v = (acc2[nt][rr] - mu[rr]) * rs[rr] * gr[nt] + ber[nt];
                atomicAdd(&seg[(size_t)rrow[rr] * HID + col], v);
            }
        }
        if (t < 64) atomicAdd(&cnt[sRecv[t]], 1.0f);
    }
}

__launch_bounds__(256)
__global__ void k_node_fb(const float* __restrict__ nfeat,
                          const float* __restrict__ seg, const float* __restrict__ cnt,
                          const u16* __restrict__ W1T, const float* __restrict__ b1v,
                          const u16* __restrict__ W2T, const float* __restrict__ b2v,
                          const float* __restrict__ g, const float* __restrict__ be,
                          const u16* __restrict__ noW1T, const float* __restrict__ nob1,
                          const float* __restrict__ noW2, const float* __restrict__ nob2,
                          float* __restrict__ outN) {
    __shared__ __align__(16) u16 sWk[2][128 * 40];
    __shared__ __align__(16) u16 sH[4][16 * 136];
    __shared__ __align__(16) u16 sNo[128 * 136];
    const int t = threadIdx.x;
    const int lane = t & 63, w = t >> 6;
    const int l15 = lane & 15, quad = lane >> 4;

    for (int i = t; i < 2048; i += 256) {
        int n = i >> 4, q = i & 15;
        *(uint4*)&sNo[n * 136 + q * 8] = *(const uint4*)&noW1T[n * 128 + q * 8];
    }
    float b1r[8], b2r[8], gr[8], ber[8], nob1r[8], w2r[8][3];
    #pragma unroll
    for (int nt = 0; nt < 8; ++nt) {
        int col = nt * 16 + l15;
        b1r[nt] = b1v[col]; b2r[nt] = b2v[col]; gr[nt] = g[col]; ber[nt] = be[col];
        nob1r[nt] = nob1[col];
        #pragma unroll
        for (int c = 0; c < 3; ++c) w2r[nt][c] = noW2[col * 3 + c];
    }
    float nob2r[3] = {nob2[0], nob2[1], nob2[2]};
    __syncthreads();

    const int NT = (N_NODES + 63) / 64;
    for (int tile = blockIdx.x; tile < NT; tile += gridDim.x) {
        const int n0 = tile * 64;
        __syncthreads();
        const int node = n0 + w * 16 + l15;
        const bool valid = node < N_NODES;
        const int nc = valid ? node : 0;
        float inv = 1.0f / fmaxf(cnt[nc], 1.0f);
        short8 a[8];
        #pragma unroll
        for (int ks = 0; ks < 4; ++ks) {
            a[ks]     = pack8(&nfeat[(size_t)nc * HID + ks * 32 + quad * 8]);
            a[4 + ks] = pack8s(&seg[(size_t)nc * HID + ks * 32 + quad * 8], inv);
        }
        #pragma unroll
        for (int i = t; i < 512; i += 256) {
            int n = i >> 2, q = i & 3;
            *(uint4*)&sWk[0][n * 40 + q * 8] = *(const uint4*)&W1T[n * 256 + q * 8];
        }
        __syncthreads();
        floatx4 acc[8];
        #pragma unroll
        for (int nt = 0; nt < 8; ++nt) acc[nt] = (floatx4){0.f, 0.f, 0.f, 0.f};
        #pragma unroll
        for (int ks = 0; ks < 8; ++ks) {
            if (ks < 7) {
                #pragma unroll
                for (int i = t; i < 512; i += 256) {
                    int n = i >> 2, q = i & 3;
                    *(uint4*)&sWk[(ks + 1) & 1][n * 40 + q * 8] =
                        *(const uint4*)&W1T[n * 256 + (ks + 1) * 32 + q * 8];
                }
            }
            const u16* B = sWk[ks & 1];
            #pragma unroll
            for (int nt = 0; nt < 8; ++nt) {
                short8 bv = *(const short8*)&B[(nt * 16 + l15) * 40 + quad * 8];
                acc[nt] = __builtin_amdgcn_mfma_f32_16x16x32_bf16(a[ks], bv, acc[nt], 0, 0, 0);
            }
            __syncthreads();
        }
        #pragma unroll
        for (int nt = 0; nt < 8; ++nt) {
            int col = nt * 16 + l15;
            #pragma unroll
            for (int rr = 0; rr < 4; ++rr)
                sH[w][(quad * 4 + rr) * 136 + col] = f2bf(siluf(acc[nt][rr] + b1r[nt]));
        }
        #pragma unroll
        for (int i = t; i < 512; i += 256) {
            int n = i >> 2, q = i & 3;
            *(uint4*)&sWk[0][n * 40 + q * 8] = *(const uint4*)&W2T[n * 128 + q * 8];
        }
        __syncthreads();
        short8 ha[4];
        #pragma unroll
        for (int ks = 0; ks < 4; ++ks)
            ha[ks] = *(const short8*)&sH[w][l15 * 136 + ks * 32 + quad * 8];
        floatx4 acc2[8];
        #pragma unroll
        for (int nt = 0; nt < 8; ++nt) acc2[nt] = (floatx4){0.f, 0.f, 0.f, 0.f};
        #pragma unroll
        for (int ks = 0; ks < 4; ++ks) {
            if (ks < 3) {
                #pragma unroll
                for (int i = t; i < 512; i += 256) {
                    int n = i >> 2, q = i & 3;
                    *(uint4*)&sWk[(ks + 1) & 1][n * 40 + q * 8] =
                        *(const uint4*)&W2T[n * 128 + (ks + 1) * 32 + q * 8];
                }
            }
            const u16* B = sWk[ks & 1];
            #pragma unroll
            for (int nt = 0; nt < 8; ++nt) {
                short8 bv = *(const short8*)&B[(nt * 16 + l15) * 40 + quad * 8];
                acc2[nt] = __builtin_amdgcn_mfma_f32_16x16x32_bf16(ha[ks], bv, acc2[nt], 0, 0, 0);
            }
            if (ks < 3) __syncthreads();
        }
        float sum[4] = {0, 0, 0, 0}, sq[4] = {0, 0, 0, 0};
        #pragma unroll
        for (int nt = 0; nt < 8; ++nt)
            #pragma unroll
            for (int rr = 0; rr < 4; ++rr) {
                float v = acc2[nt][rr] + b2r[nt];
                acc2[nt][rr] = v; sum[rr] += v; sq[rr] += v * v;
            }
        #pragma unroll
        for (int m = 1; m < 16; m <<= 1)
            #pragma unroll
            for (int rr = 0; rr < 4; ++rr) {
                sum[rr] += __shfl_xor(sum[rr], m);
                sq[rr]  += __shfl_xor(sq[rr], m);
            }
        #pragma unroll
        for (int nt = 0; nt < 8; ++nt) {
            int col = nt * 16 + l15;
            #pragma unroll
            for (int rr = 0; rr < 4; ++rr) {
                float mu = sum[rr] * (1.0f / HID);
                float var = fmaxf(sq[rr] * (1.0f / HID) - mu * mu, 0.f);
                float rsn = rsqrtf(var + LN_EPS);
                sH[w][(quad * 4 + rr) * 136 + col] =
                    f2bf((acc2[nt][rr] - mu) * rsn * gr[nt] + ber[nt]);
            }
        }
        __syncthreads();
        short8 h2[4];
        #pragma unroll
        for (int ks = 0; ks < 4; ++ks)
            h2[ks] = *(const short8*)&sH[w][l15 * 136 + ks * 32 + quad * 8];
        floatx4 acc3[8];
        #pragma unroll
        for (int nt = 0; nt < 8; ++nt) acc3[nt] = (floatx4){0.f, 0.f, 0.f, 0.f};
        #pragma unroll
        for (int ks = 0; ks < 4; ++ks) {
            #pragma unroll
            for (int nt = 0; nt < 8; ++nt) {
                short8 bv = *(const short8*)&sNo[(nt * 16 + l15) * 136 + ks * 32 + quad * 8];
                acc3[nt] = __builtin_amdgcn_mfma_f32_16x16x32_bf16(h2[ks], bv, acc3[nt], 0, 0, 0);
            }
        }
        float p[4][3] = {{0,0,0},{0,0,0},{0,0,0},{0,0,0}};
        #pragma unroll
        for (int nt = 0; nt < 8; ++nt)
            #pragma unroll
            for (int rr = 0; rr < 4; ++rr) {
                float h3 = sigmf(acc3[nt][rr] + nob1r[nt]);
                #pragma unroll
                for (int c = 0; c < 3; ++c) p[rr][c] += h3 * w2r[nt][c];
            }
        #pragma unroll
        for (int m = 1; m < 16; m <<= 1)
            #pragma unroll
            for (int rr = 0; rr < 4; ++rr)
                #pragma unroll
                for (int c = 0; c < 3; ++c) p[rr][c] += __shfl_xor(p[rr][c], m);
        if (l15 < 3) {
            #pragma unroll
            for (int rr = 0; rr < 4; ++rr) {
                int row = n0 + w * 16 + quad * 4 + rr;
                if (row < N_NODES) outN[(size_t)row * 3 + l15] = p[rr][l15] + nob2r[l15];
            }
        }
    }
}

extern "C" void kernel_launch(void* const* d_in, const int* in_sizes, int n_in,
                              void* d_out, int out_size, void* d_ws, size_t ws_size,
                              hipStream_t stream) {
    const int*   eidx  = (const int*)d_in[0];
    const float* ef    = (const float*)d_in[1];
    const float* nlat  = (const float*)d_in[2];
    const float* nfeat = (const float*)d_in[3];
    const float* eeW1 = (const float*)d_in[4];
    const float* eeb1 = (const float*)d_in[5];
    const float* eeW2 = (const float*)d_in[6];
    const float* eeb2 = (const float*)d_in[7];
    const float* eeg  = (const float*)d_in[8];
    const float* eebe = (const float*)d_in[9];
    const float* peW1 = (const float*)d_in[10];
    const float* peb1 = (const float*)d_in[11];
    const float* peW2 = (const float*)d_in[12];
    const float* peb2 = (const float*)d_in[13];
    const float* peg  = (const float*)d_in[14];
    const float* pebe = (const float*)d_in[15];
    const float* pnW1 = (const float*)d_in[16];
    const float* pnb1 = (const float*)d_in[17];
    const float* pnW2 = (const float*)d_in[18];
    const float* pnb2 = (const float*)d_in[19];
    const float* png_ = (const float*)d_in[20];
    const float* pnbe = (const float*)d_in[21];
    const float* noW1 = (const float*)d_in[22];
    const float* nob1 = (const float*)d_in[23];
    const float* noW2 = (const float*)d_in[24];
    const float* nob2 = (const float*)d_in[25];

    char* ws = (char*)d_ws;
    float* seg = (float*)ws;                                  // 25,600,000
    float* cnt = (float*)(ws + 25600000);                     //    200,000
    u16* eeW2T = (u16*)(ws + 25800000);                       //     32,768
    u16* peW1T = (u16*)(ws + 25832768);                       //     98,304
    u16* peW2T = (u16*)(ws + 25931072);                       //     32,768
    u16* pnW1T = (u16*)(ws + 25963840);                       //     65,536
    u16* pnW2T = (u16*)(ws + 26029376);                       //     32,768
    u16* noW1T = (u16*)(ws + 26062144);                       //     32,768
    u16* P1    = (u16*)(ws + 26094912);                       // 12,800,000 (bf16; also Q1)
    u16* P2    = (u16*)(ws + 38894912);                       // 12,800,000 (bf16)
    const size_t WS_NEED = 51694912;
    const bool useP = ws_size >= WS_NEED;

    hipMemsetAsync(ws, 0, 25800000, stream);

    k_prepT<<<64, 256, 0, stream>>>(eeW2, eeW2T, 128, 128);
    k_prepT<<<192, 256, 0, stream>>>(peW1, peW1T, 384, 128);
    k_prepT<<<64, 256, 0, stream>>>(peW2, peW2T, 128, 128);
    k_prepT<<<128, 256, 0, stream>>>(pnW1, pnW1T, 256, 128);
    k_prepT<<<64, 256, 0, stream>>>(pnW2, pnW2T, 128, 128);
    k_prepT<<<64, 256, 0, stream>>>(noW1, noW1T, 128, 128);

    float* outEL = (float*)d_out;
    float* outN  = outEL + (size_t)N_EDGES * HID;

    k_edge_ee<<<1024, 256, 0, stream>>>(ef, eeW1, eeb1, eeW2T, eeb2, eeg, eebe, outEL);

    if (useP) {
        k_gemm128<<<512, 256, 0, stream>>>(nlat,  peW1T, 384, 0,   P1);  // P1 = nlat@peW1a
        k_gemm128<<<512, 256, 0, stream>>>(nfeat, peW1T, 384, 128, P2);  // P2 = nfeat@peW1b
        k_edge_pe<<<1024, 256, 0, stream>>>(eidx, P1, P2, outEL, peW1T, peb1, peW2T, peb2,
                                            peg, pebe, seg, cnt);
        k_gemm128<<<512, 256, 0, stream>>>(nfeat, pnW1T, 256, 0, P1);    // Q1 = nfeat@pnW1a
        k_node<<<782, 256, 0, stream>>>(P1, seg, cnt, pnW1T, pnb1, pnW2T, pnb2, png_, pnbe,
                                        noW1T, nob1, noW2, nob2, outN);
    } else {
        k_edge_pe_fb<<<768, 256, 0, stream>>>(eidx, nlat, nfeat, outEL, peW1T, peb1,
                                              peW2T, peb2, peg, pebe, seg, cnt);
        k_node_fb<<<782, 256, 0, stream>>>(nfeat, seg, cnt, pnW1T, pnb1, pnW2T, pnb2,
                                           png_, pnbe, noW1T, nob1, noW2, nob2, outN);
    }
}